// Round 6
// baseline (41089.517 us; speedup 1.0000x reference)
//
#include <hip/hip_runtime.h>
#include <math.h>

#define TT 200
#define BB 512
#define DD 40
#define HH 400
#define NC 12
#define NBLK 250
#define NTHR 256

// All activations stored TRANSPOSED [HH][BB] (k-major) so per-k loads are
// coalesced across threads (thread tid owns batch column b = q*256+tid).
// Weight slices [K][16 cols] live in LDS for all 200 steps (wave-uniform
// broadcast reads). Schedule identical to round-5 (passed):
//  beta(t):  rt1,zt1,ah1p (layer1 gates), rt0n,zt0n (layer0 gates for t+1)
//  alpha(t): h1(t) combine; h0'(t+1) combine; idle blocks transpose x(t+2)
// 125 beta keys (m*25+coltile) x 2 batch-halves = 250 blocks; alpha on 100.

struct P {
  const float *x;
  const float *Wh0,*bh0,*Wz0,*bz0,*Wr0,*br0,*Uh0,*Uz0,*Ur0;
  const float *Wh1,*bh1,*Wz1,*bz1,*Wr1,*br1,*Uh1,*Uz1,*Ur1;
  const float *Wfc,*bfc;
  float *h0a,*h0b,*h1a,*h1b;          // ping-pong states, [HH][BB]
  float *rt1,*zt1,*ah1p,*rt0n,*zt0n;  // gate buffers, [HH][BB]
  float *xta,*xtb;                    // x(t) transposed [DD][BB]; slot = t&1
  unsigned *bar;
  float *out;
};

__device__ __forceinline__ float sigq(float x){
  float v = rintf(x * 12.4f) / 31.0f;
  return fminf(fmaxf(v, 0.0f), 1.0f);
}
__device__ __forceinline__ float tanhq(float x){
  float v = rintf(x * 31.0f) / 31.0f;
  return fminf(fmaxf(v, -1.0f), 1.0f);
}

// ---- LDS weight slice loader: dst[k*16+c] = Wg[(j0+c)*ldw + k] ----
__device__ void load_slice(float* dst, const float* __restrict__ Wg, int ldw,
                           int j0, int K, int tid){
  const int c  = tid & 15;
  const int kb = tid >> 4;    // 16 k-lanes
  for (int k = kb; k < K; k += 16)
    dst[k*16 + c] = Wg[(size_t)(j0 + c)*ldw + k];
}

// acc[c] += sum_k A[k][b] * Wl[k*16+c]   (A k-major, coalesced; W broadcast)
__device__ __forceinline__ void gaccT(const float* __restrict__ A,
                                      const float* __restrict__ Wl,
                                      int b, int K, float acc[16]){
  const float* ap = A + b;
  const int K4 = K >> 2;
  #pragma unroll 2
  for (int g = 0; g < K4; ++g) {
    float a[4];
    #pragma unroll
    for (int kk = 0; kk < 4; ++kk) a[kk] = ap[(size_t)(g*4+kk)*BB];
    #pragma unroll
    for (int kk = 0; kk < 4; ++kk) {
      const float4* w = (const float4*)(Wl + (g*4+kk)*16);
      float4 w0 = w[0], w1 = w[1], w2 = w[2], w3 = w[3];
      float av = a[kk];
      acc[0] +=av*w0.x; acc[1] +=av*w0.y; acc[2] +=av*w0.z; acc[3] +=av*w0.w;
      acc[4] +=av*w1.x; acc[5] +=av*w1.y; acc[6] +=av*w1.z; acc[7] +=av*w1.w;
      acc[8] +=av*w2.x; acc[9] +=av*w2.y; acc[10]+=av*w2.z; acc[11]+=av*w2.w;
      acc[12]+=av*w3.x; acc[13]+=av*w3.y; acc[14]+=av*w3.z; acc[15]+=av*w3.w;
    }
  }
}

// acc[c] += sum_k (Ap[k][b]*Am[k][b]) * Wl[k*16+c]
__device__ __forceinline__ void paccT(const float* __restrict__ Ap,
                                      const float* __restrict__ Am,
                                      const float* __restrict__ Wl,
                                      int b, int K, float acc[16]){
  const float* pp = Ap + b;
  const float* mp = Am + b;
  const int K4 = K >> 2;
  #pragma unroll 2
  for (int g = 0; g < K4; ++g) {
    float a[4];
    #pragma unroll
    for (int kk = 0; kk < 4; ++kk)
      a[kk] = pp[(size_t)(g*4+kk)*BB] * mp[(size_t)(g*4+kk)*BB];
    #pragma unroll
    for (int kk = 0; kk < 4; ++kk) {
      const float4* w = (const float4*)(Wl + (g*4+kk)*16);
      float4 w0 = w[0], w1 = w[1], w2 = w[2], w3 = w[3];
      float av = a[kk];
      acc[0] +=av*w0.x; acc[1] +=av*w0.y; acc[2] +=av*w0.z; acc[3] +=av*w0.w;
      acc[4] +=av*w1.x; acc[5] +=av*w1.y; acc[6] +=av*w1.z; acc[7] +=av*w1.w;
      acc[8] +=av*w2.x; acc[9] +=av*w2.y; acc[10]+=av*w2.z; acc[11]+=av*w2.w;
      acc[12]+=av*w3.x; acc[13]+=av*w3.y; acc[14]+=av*w3.z; acc[15]+=av*w3.w;
    }
  }
}

// transpose one feature d of x(step) into dst[d][b]
__device__ void xpose(const float* __restrict__ xsrc, float* dst, int d, int tid){
  for (int b = tid; b < BB; b += NTHR)
    dst[d*BB + b] = xsrc[(size_t)b*DD + d];
}

// ---- phase bodies (thread owns batch col b, 16 output cols c0..c0+15) ----
__device__ void beta_wave(const P& p, int t, int bm, int c0, int b,
                          const float* Wb0, const float* Wb1){
  const float* h0n = (t & 1) ? p.h0b : p.h0a;   // h0'(t)
  const float* h1c = (t & 1) ? p.h1b : p.h1a;   // h1(t-1)
  const float* xt1 = (t & 1) ? p.xta : p.xtb;   // xT(t+1), slot (t+1)&1

  float acc[16] = {};
  const float* bias; float* out; int act = 1;
  if (bm == 0)      { gaccT(h1c,Wb0,b,HH,acc); gaccT(h0n,Wb1,b,HH,acc); bias=p.br1; out=p.rt1; }
  else if (bm == 1) { gaccT(h1c,Wb0,b,HH,acc); gaccT(h0n,Wb1,b,HH,acc); bias=p.bz1; out=p.zt1; }
  else if (bm == 2) { gaccT(h0n,Wb0,b,HH,acc); bias=p.bh1; out=p.ah1p; act=0; }
  else if (bm == 3) { gaccT(h0n,Wb0,b,HH,acc); gaccT(xt1,Wb1,b,DD,acc); bias=p.br0; out=p.rt0n; }
  else              { gaccT(h0n,Wb0,b,HH,acc); gaccT(xt1,Wb1,b,DD,acc); bias=p.bz0; out=p.zt0n; }

  #pragma unroll
  for (int c = 0; c < 16; ++c) {
    float v = acc[c] + bias[c0+c];
    out[(size_t)(c0+c)*BB + b] = act ? sigq(v) : v;
  }
}

__device__ void alpha_wave(const P& p, int t, int am, int c0, int b,
                           const float* Wa, const float* Wa2){
  const float* h0n = (t & 1) ? p.h0b : p.h0a;
  const float* h1c = (t & 1) ? p.h1b : p.h1a;
  float* h0w = (t & 1) ? p.h0a : p.h0b;
  float* h1w = (t & 1) ? p.h1a : p.h1b;
  const float* xt1 = (t & 1) ? p.xta : p.xtb;

  float acc[16] = {};
  if (am == 0) {
    paccT(p.rt1, h1c, Wa, b, HH, acc);
    #pragma unroll
    for (int c = 0; c < 16; ++c) {
      size_t idx = (size_t)(c0+c)*BB + b;
      float at = acc[c] + p.ah1p[idx];
      float z = p.zt1[idx], hv = h1c[idx];
      h1w[idx] = z*hv + (1.0f - z)*tanhq(at);
    }
  } else {
    paccT(p.rt0n, h0n, Wa, b, HH, acc);
    gaccT(xt1, Wa2, b, DD, acc);
    #pragma unroll
    for (int c = 0; c < 16; ++c) {
      size_t idx = (size_t)(c0+c)*BB + b;
      float at = acc[c] + p.bh0[c0+c];
      float z = p.zt0n[idx], hv = h0n[idx];
      h0w[idx] = z*hv + (1.0f - z)*tanhq(at);
    }
  }
}

// prologue: h0'(0) = (1 - sigq(Wz0 x0 + bz0)) * tanhq(Wh0 x0 + bh0); h0(-1)=0
__device__ void pro_wave(const P& p, int c0, int b){
  float az[16] = {}, ah[16] = {};
  for (int d = 0; d < DD; ++d) {
    float av = p.xta[d*BB + b];
    #pragma unroll
    for (int c = 0; c < 16; ++c) {
      az[c] += av * p.Wz0[(size_t)(c0+c)*DD + d];
      ah[c] += av * p.Wh0[(size_t)(c0+c)*DD + d];
    }
  }
  #pragma unroll
  for (int c = 0; c < 16; ++c) {
    float z = sigq(az[c] + p.bz0[c0+c]);
    float a = ah[c] + p.bh0[c0+c];
    p.h0a[(size_t)(c0+c)*BB + b] = (1.0f - z)*tanhq(a);
  }
}

__device__ void fc_wave(const P& p, int b, int lane){
  const float* h1 = p.h1a;    // h1(199): t=199 odd -> h1a, [HH][BB]
  float l[NC];
  #pragma unroll
  for (int cI = 0; cI < NC; ++cI) {
    float sm = 0.0f;
    for (int k = lane; k < HH; k += 64)
      sm += h1[(size_t)k*BB + b] * p.Wfc[(size_t)cI*HH + k];
    #pragma unroll
    for (int off = 32; off > 0; off >>= 1)
      sm += __shfl_xor(sm, off);
    l[cI] = sm + p.bfc[cI];
  }
  float mx = l[0];
  #pragma unroll
  for (int cI = 1; cI < NC; ++cI) mx = fmaxf(mx, l[cI]);
  float sum = 0.0f;
  #pragma unroll
  for (int cI = 0; cI < NC; ++cI) { l[cI] = expf(l[cI] - mx); sum += l[cI]; }
  float inv = 1.0f / sum;
  if (lane == 0) {
    #pragma unroll
    for (int cI = 0; cI < NC; ++cI) p.out[(size_t)b*NC + cI] = l[cI] * inv;
  }
}

// ---- grid barrier: 16 spaced counters -> master -> generation (monotone) ----
__device__ void gbar(int bn, unsigned* bar, int u){
  __syncthreads();
  if (threadIdx.x == 0) {
    __threadfence();
    const int i = u & 15;
    const int quota = (NBLK >> 4) + ((i < (NBLK & 15)) ? 1 : 0);
    unsigned* c0  = bar + i*32;
    unsigned* c1  = bar + 512;
    unsigned* gen = bar + 544;
    unsigned v = __hip_atomic_fetch_add(c0, 1u, __ATOMIC_RELEASE, __HIP_MEMORY_SCOPE_AGENT);
    if (v + 1u == (unsigned)quota * (unsigned)(bn+1)) {
      unsigned w2 = __hip_atomic_fetch_add(c1, 1u, __ATOMIC_ACQ_REL, __HIP_MEMORY_SCOPE_AGENT);
      if (w2 + 1u == 16u * (unsigned)(bn+1))
        __hip_atomic_store(gen, (unsigned)(bn+1), __ATOMIC_RELEASE, __HIP_MEMORY_SCOPE_AGENT);
    }
    while (__hip_atomic_load(gen, __ATOMIC_RELAXED, __HIP_MEMORY_SCOPE_AGENT) < (unsigned)(bn+1))
      __builtin_amdgcn_s_sleep(2);
    __threadfence();
  }
  __syncthreads();
}

// ---- LDS loaders ----
__device__ void load_beta_lds(const P& p, int bm, int j0, float* Wb0, float* Wb1, int tid){
  if (bm == 0)      { load_slice(Wb0, p.Ur1, HH, j0, HH, tid); load_slice(Wb1, p.Wr1, HH, j0, HH, tid); }
  else if (bm == 1) { load_slice(Wb0, p.Uz1, HH, j0, HH, tid); load_slice(Wb1, p.Wz1, HH, j0, HH, tid); }
  else if (bm == 2) { load_slice(Wb0, p.Wh1, HH, j0, HH, tid); }
  else if (bm == 3) { load_slice(Wb0, p.Ur0, HH, j0, HH, tid); load_slice(Wb1, p.Wr0, DD, j0, DD, tid); }
  else              { load_slice(Wb0, p.Uz0, HH, j0, HH, tid); load_slice(Wb1, p.Wz0, DD, j0, DD, tid); }
}
__device__ void load_alpha_lds(const P& p, int am, int j0, float* Wa, float* Wa2, int tid){
  if (am == 0) load_slice(Wa, p.Uh1, HH, j0, HH, tid);
  else       { load_slice(Wa, p.Uh0, HH, j0, HH, tid); load_slice(Wa2, p.Wh0, DD, j0, DD, tid); }
}

// ---- persistent cooperative kernel ----
__global__ __launch_bounds__(NTHR, 2) void gru_coop(P p){
  __shared__ float lds[19840];   // Wb0 | Wb1 | Wa | Wa2 = 79,360 B
  float* Wb0 = lds;
  float* Wb1 = lds + 6400;
  float* Wa  = lds + 12800;
  float* Wa2 = lds + 19200;

  const int u   = blockIdx.x;
  const int tid = threadIdx.x;
  const int bk  = u >> 1;                 // beta key 0..124
  const int bm  = bk / 25, bc0 = (bk % 25) * 16;
  const int am  = bk / 25, ac0 = bc0;     // alpha key valid for u<100 (ak = u>>1)
  const int b   = (u & 1)*256 + tid;      // owned batch column

  load_beta_lds(p, bm, bc0, Wb0, Wb1, tid);
  if (u < 100) load_alpha_lds(p, am, ac0, Wa, Wa2, tid);

  // phase 0: transpose x(0)->xta, x(1)->xtb
  if (u < 40)       xpose(p.x,                       p.xta, u,      tid);
  else if (u < 80)  xpose(p.x + (size_t)BB*DD,       p.xtb, u - 40, tid);
  int bn = 0;
  gbar(bn++, p.bar, u);
  if (u < 50) pro_wave(p, (u >> 1)*16, b);
  gbar(bn++, p.bar, u);

  for (int t = 0; t < TT; ++t) {
    beta_wave(p, t, bm, bc0, b, Wb0, Wb1);
    gbar(bn++, p.bar, u);
    if (u < 100) alpha_wave(p, t, am, ac0, b, Wa, Wa2);
    else if (u < 140)
      xpose(p.x + (size_t)((t+2) % TT)*BB*DD, (t & 1) ? p.xtb : p.xta, u - 100, tid);
    gbar(bn++, p.bar, u);
  }
  if (u < 128) fc_wave(p, u*4 + (tid >> 6), tid & 63);
}

// ---- fallback regular-launch path (same device functions) ----
__global__ __launch_bounds__(NTHR) void k_init(P p){
  const int u = blockIdx.x, tid = threadIdx.x;
  if (u < 40)      xpose(p.x,                 p.xta, u,      tid);
  else if (u < 80) xpose(p.x + (size_t)BB*DD, p.xtb, u - 40, tid);
}
__global__ __launch_bounds__(NTHR) void k_pro(P p){
  const int u = blockIdx.x;
  pro_wave(p, (u >> 1)*16, (u & 1)*256 + threadIdx.x);
}
__global__ __launch_bounds__(NTHR) void k_beta(P p, int t){
  __shared__ float lds[12800];
  const int u = blockIdx.x, tid = threadIdx.x;
  const int bk = u >> 1, bm = bk / 25, bc0 = (bk % 25) * 16;
  load_beta_lds(p, bm, bc0, lds, lds + 6400, tid);
  __syncthreads();
  beta_wave(p, t, bm, bc0, (u & 1)*256 + tid, lds, lds + 6400);
}
__global__ __launch_bounds__(NTHR) void k_alpha(P p, int t){
  __shared__ float lds[7040];
  const int u = blockIdx.x, tid = threadIdx.x;
  if (u < 100) {
    const int ak = u >> 1, am = ak / 25, ac0 = (ak % 25) * 16;
    load_alpha_lds(p, am, ac0, lds, lds + 6400, tid);
    __syncthreads();
    alpha_wave(p, t, am, ac0, (u & 1)*256 + tid, lds, lds + 6400);
  } else if (u < 140) {
    xpose(p.x + (size_t)((t+2) % TT)*BB*DD, (t & 1) ? p.xtb : p.xta, u - 100, tid);
  }
}
__global__ __launch_bounds__(NTHR) void k_fc(P p){
  fc_wave(p, blockIdx.x*4 + (threadIdx.x >> 6), threadIdx.x & 63);
}

extern "C" void kernel_launch(void* const* d_in, const int* in_sizes, int n_in,
                              void* d_out, int out_size, void* d_ws, size_t ws_size,
                              hipStream_t stream) {
  P p;
  p.x   = (const float*)d_in[0];
  p.Wh0 = (const float*)d_in[1];  p.bh0 = (const float*)d_in[2];
  p.Wz0 = (const float*)d_in[3];  p.bz0 = (const float*)d_in[4];
  p.Wr0 = (const float*)d_in[5];  p.br0 = (const float*)d_in[6];
  p.Uh0 = (const float*)d_in[7];  p.Uz0 = (const float*)d_in[8];  p.Ur0 = (const float*)d_in[9];
  p.Wh1 = (const float*)d_in[10]; p.bh1 = (const float*)d_in[11];
  p.Wz1 = (const float*)d_in[12]; p.bz1 = (const float*)d_in[13];
  p.Wr1 = (const float*)d_in[14]; p.br1 = (const float*)d_in[15];
  p.Uh1 = (const float*)d_in[16]; p.Uz1 = (const float*)d_in[17]; p.Ur1 = (const float*)d_in[18];
  p.Wfc = (const float*)d_in[19]; p.bfc = (const float*)d_in[20];

  float* ws = (float*)d_ws;
  const size_t SZ = (size_t)BB * HH;
  p.h0a  = ws + 0*SZ;  p.h0b  = ws + 1*SZ;
  p.h1a  = ws + 2*SZ;  p.h1b  = ws + 3*SZ;
  p.rt1  = ws + 4*SZ;  p.zt1  = ws + 5*SZ;  p.ah1p = ws + 6*SZ;
  p.rt0n = ws + 7*SZ;  p.zt0n = ws + 8*SZ;
  p.xta  = ws + 9*SZ;
  p.xtb  = p.xta + (size_t)BB*DD;
  p.bar  = (unsigned*)(p.xtb + (size_t)BB*DD);
  p.out  = (float*)d_out;

  hipMemsetAsync(p.h1a, 0, SZ*sizeof(float), stream);   // h1(-1) = 0
  hipMemsetAsync(p.bar, 0, 4096, stream);               // barrier state

  void* args[] = { &p };
  hipError_t err = hipLaunchCooperativeKernel((const void*)gru_coop, dim3(NBLK),
                                              dim3(NTHR), args, 0, stream);
  if (err != hipSuccess) {
    k_init<<<dim3(80), dim3(NTHR), 0, stream>>>(p);
    k_pro<<<dim3(50), dim3(NTHR), 0, stream>>>(p);
    for (int t = 0; t < TT; ++t) {
      k_beta <<<dim3(NBLK), dim3(NTHR), 0, stream>>>(p, t);
      k_alpha<<<dim3(140),  dim3(NTHR), 0, stream>>>(p, t);
    }
    k_fc<<<dim3(128), dim3(NTHR), 0, stream>>>(p);
  }
}

// Round 7
// 27753.436 us; speedup vs baseline: 1.4805x; 1.4805x over previous
//
#include <hip/hip_runtime.h>
#include <math.h>

#define TT 200
#define BB 512
#define DD 40
#define HH 400
#define NC 12
#define GRP 4
#define GB 125            // blocks per group
#define NBLK (GRP*GB)     // 500
#define NTHR 256
#define GCOLS 128         // batch columns per group

// Batch is embarrassingly parallel (GEMM reduces over hidden k, not batch):
// 4 independent groups x 128 cols, each with its OWN 125-block barrier.
// Group roles (r = u % GB):
//   beta (all r):  bm=r/25 (0=rt1,1=zt1,2=ah1p,3=rt0n,4=zt0n), coltile=r%25
//   alpha (r<50):  am=r/25 (0=h1 combine, 1=h0' combine), coltile=r%25
//   xpose (50<=r<90): row d=r-50 of x(t+2) -> slot (t&1), group col-slice
//   pro   (50<=r<75): coltile=r-50
//   fc    (r<32):  cols gbase + r*4 + wave
// Activations [HH][BB] k-major; thread owns col b=gbase+(tid&127), 8 out-cols
// (ch=tid>>7 picks which 8 of the block's 16). Weight slices [K][16] in LDS.

struct P {
  const float *x;
  const float *Wh0,*bh0,*Wz0,*bz0,*Wr0,*br0,*Uh0,*Uz0,*Ur0;
  const float *Wh1,*bh1,*Wz1,*bz1,*Wr1,*br1,*Uh1,*Uz1,*Ur1;
  const float *Wfc,*bfc;
  float *h0a,*h0b,*h1a,*h1b;
  float *rt1,*zt1,*ah1p,*rt0n,*zt0n;
  float *xta,*xtb;
  unsigned *bar;
  float *out;
};

__device__ __forceinline__ float sigq(float x){
  float v = rintf(x * 12.4f) / 31.0f;
  return fminf(fmaxf(v, 0.0f), 1.0f);
}
__device__ __forceinline__ float tanhq(float x){
  float v = rintf(x * 31.0f) / 31.0f;
  return fminf(fmaxf(v, -1.0f), 1.0f);
}

// dst[k*16+c] = Wg[(j0+c)*ldw + k]
__device__ void load_slice(float* dst, const float* __restrict__ Wg, int ldw,
                           int j0, int K, int tid){
  const int c  = tid & 15;
  const int kb = tid >> 4;
  for (int k = kb; k < K; k += 16)
    dst[k*16 + c] = Wg[(size_t)(j0 + c)*ldw + k];
}

// acc[c] += sum_k A[k][b] * Wl[k*16+c], c=0..7 (Wl pre-offset by ch*8)
__device__ __forceinline__ void gaccT8(const float* __restrict__ A,
                                       const float* __restrict__ Wl,
                                       int b, int K, float acc[8]){
  const float* ap = A + b;
  const int K8 = K >> 3;
  for (int g = 0; g < K8; ++g) {
    float a[8];
    #pragma unroll
    for (int kk = 0; kk < 8; ++kk) a[kk] = ap[(size_t)(g*8+kk)*BB];
    #pragma unroll
    for (int kk = 0; kk < 8; ++kk) {
      const float4 w0 = *(const float4*)(Wl + (g*8+kk)*16);
      const float4 w1 = *(const float4*)(Wl + (g*8+kk)*16 + 4);
      float av = a[kk];
      acc[0]+=av*w0.x; acc[1]+=av*w0.y; acc[2]+=av*w0.z; acc[3]+=av*w0.w;
      acc[4]+=av*w1.x; acc[5]+=av*w1.y; acc[6]+=av*w1.z; acc[7]+=av*w1.w;
    }
  }
}

// acc[c] += sum_k (Ap[k][b]*Am[k][b]) * Wl[k*16+c]
__device__ __forceinline__ void paccT8(const float* __restrict__ Ap,
                                       const float* __restrict__ Am,
                                       const float* __restrict__ Wl,
                                       int b, int K, float acc[8]){
  const float* pp = Ap + b;
  const float* mp = Am + b;
  const int K8 = K >> 3;
  for (int g = 0; g < K8; ++g) {
    float a[8];
    #pragma unroll
    for (int kk = 0; kk < 8; ++kk)
      a[kk] = pp[(size_t)(g*8+kk)*BB] * mp[(size_t)(g*8+kk)*BB];
    #pragma unroll
    for (int kk = 0; kk < 8; ++kk) {
      const float4 w0 = *(const float4*)(Wl + (g*8+kk)*16);
      const float4 w1 = *(const float4*)(Wl + (g*8+kk)*16 + 4);
      float av = a[kk];
      acc[0]+=av*w0.x; acc[1]+=av*w0.y; acc[2]+=av*w0.z; acc[3]+=av*w0.w;
      acc[4]+=av*w1.x; acc[5]+=av*w1.y; acc[6]+=av*w1.z; acc[7]+=av*w1.w;
    }
  }
}

// transpose row d of x(step) into dst[d][gbase..gbase+127]
__device__ void xpose_g(const float* __restrict__ xsrc, float* dst, int d,
                        int gbase, int tid){
  if (tid < GCOLS)
    dst[d*BB + gbase + tid] = xsrc[(size_t)(gbase + tid)*DD + d];
}

__device__ void beta_wave(const P& p, int t, int bm, int c0, int b,
                          const float* Wb0, const float* Wb1){
  const float* h0n = (t & 1) ? p.h0b : p.h0a;   // h0'(t)
  const float* h1c = (t & 1) ? p.h1b : p.h1a;   // h1(t-1)
  const float* xt1 = (t & 1) ? p.xta : p.xtb;   // xT(t+1)

  float acc[8] = {};
  const float* bias; float* out; int act = 1;
  if (bm == 0)      { gaccT8(h1c,Wb0,b,HH,acc); gaccT8(h0n,Wb1,b,HH,acc); bias=p.br1; out=p.rt1; }
  else if (bm == 1) { gaccT8(h1c,Wb0,b,HH,acc); gaccT8(h0n,Wb1,b,HH,acc); bias=p.bz1; out=p.zt1; }
  else if (bm == 2) { gaccT8(h0n,Wb0,b,HH,acc); bias=p.bh1; out=p.ah1p; act=0; }
  else if (bm == 3) { gaccT8(h0n,Wb0,b,HH,acc); gaccT8(xt1,Wb1,b,DD,acc); bias=p.br0; out=p.rt0n; }
  else              { gaccT8(h0n,Wb0,b,HH,acc); gaccT8(xt1,Wb1,b,DD,acc); bias=p.bz0; out=p.zt0n; }

  #pragma unroll
  for (int c = 0; c < 8; ++c) {
    float v = acc[c] + bias[c0+c];
    out[(size_t)(c0+c)*BB + b] = act ? sigq(v) : v;
  }
}

__device__ void alpha_wave(const P& p, int t, int am, int c0, int b,
                           const float* Wa, const float* Wa2){
  const float* h0n = (t & 1) ? p.h0b : p.h0a;
  const float* h1c = (t & 1) ? p.h1b : p.h1a;
  float* h0w = (t & 1) ? p.h0a : p.h0b;
  float* h1w = (t & 1) ? p.h1a : p.h1b;
  const float* xt1 = (t & 1) ? p.xta : p.xtb;

  float acc[8] = {};
  if (am == 0) {
    paccT8(p.rt1, h1c, Wa, b, HH, acc);
    #pragma unroll
    for (int c = 0; c < 8; ++c) {
      size_t idx = (size_t)(c0+c)*BB + b;
      float at = acc[c] + p.ah1p[idx];
      float z = p.zt1[idx], hv = h1c[idx];
      h1w[idx] = z*hv + (1.0f - z)*tanhq(at);
    }
  } else {
    paccT8(p.rt0n, h0n, Wa, b, HH, acc);
    gaccT8(xt1, Wa2, b, DD, acc);
    #pragma unroll
    for (int c = 0; c < 8; ++c) {
      size_t idx = (size_t)(c0+c)*BB + b;
      float at = acc[c] + p.bh0[c0+c];
      float z = p.zt0n[idx], hv = h0n[idx];
      h0w[idx] = z*hv + (1.0f - z)*tanhq(at);
    }
  }
}

// h0'(0) = (1 - sigq(Wz0 x0 + bz0)) * tanhq(Wh0 x0 + bh0); h0(-1)=0
__device__ void pro_wave(const P& p, int coltile, int ch, int b){
  const int c0 = coltile*16 + ch*8;
  float az[8] = {}, ah[8] = {};
  for (int d = 0; d < DD; ++d) {
    float av = p.xta[d*BB + b];
    #pragma unroll
    for (int c = 0; c < 8; ++c) {
      az[c] += av * p.Wz0[(size_t)(c0+c)*DD + d];
      ah[c] += av * p.Wh0[(size_t)(c0+c)*DD + d];
    }
  }
  #pragma unroll
  for (int c = 0; c < 8; ++c) {
    float z = sigq(az[c] + p.bz0[c0+c]);
    float a = ah[c] + p.bh0[c0+c];
    p.h0a[(size_t)(c0+c)*BB + b] = (1.0f - z)*tanhq(a);
  }
}

__device__ void fc_wave(const P& p, int b, int lane){
  const float* h1 = p.h1a;    // h1(199): t=199 odd -> h1a
  float l[NC];
  #pragma unroll
  for (int cI = 0; cI < NC; ++cI) {
    float sm = 0.0f;
    for (int k = lane; k < HH; k += 64)
      sm += h1[(size_t)k*BB + b] * p.Wfc[(size_t)cI*HH + k];
    #pragma unroll
    for (int off = 32; off > 0; off >>= 1)
      sm += __shfl_xor(sm, off);
    l[cI] = sm + p.bfc[cI];
  }
  float mx = l[0];
  #pragma unroll
  for (int cI = 1; cI < NC; ++cI) mx = fmaxf(mx, l[cI]);
  float sum = 0.0f;
  #pragma unroll
  for (int cI = 0; cI < NC; ++cI) { l[cI] = expf(l[cI] - mx); sum += l[cI]; }
  float inv = 1.0f / sum;
  if (lane == 0) {
    #pragma unroll
    for (int cI = 0; cI < NC; ++cI) p.out[(size_t)b*NC + cI] = l[cI] * inv;
  }
}

// ---- per-group barrier: 8 spread arrival counters -> master -> 8 broadcast
// lines (<=16 pollers each). Monotone counts; B = group's 4KB region.
__device__ void gbar(int bn, unsigned* B, int r){
  __syncthreads();
  if (threadIdx.x == 0) {
    __threadfence();                       // release: L2 writeback
    const int i = r & 7;
    const unsigned target = (unsigned)(bn + 1);
    const unsigned quota = 15u + (i < 5 ? 1u : 0u);   // 125 = 5*16 + 3*15
    unsigned v = __hip_atomic_fetch_add(B + i*32, 1u, __ATOMIC_RELEASE,
                                        __HIP_MEMORY_SCOPE_AGENT);
    if (v + 1u == quota * target) {
      unsigned w2 = __hip_atomic_fetch_add(B + 256, 1u, __ATOMIC_ACQ_REL,
                                           __HIP_MEMORY_SCOPE_AGENT);
      if (w2 + 1u == 8u * target) {
        #pragma unroll
        for (int j = 0; j < 8; ++j)
          __hip_atomic_store(B + 320 + j*32, target, __ATOMIC_RELEASE,
                             __HIP_MEMORY_SCOPE_AGENT);
      }
    }
    while (__hip_atomic_load(B + 320 + i*32, __ATOMIC_RELAXED,
                             __HIP_MEMORY_SCOPE_AGENT) < target)
      __builtin_amdgcn_s_sleep(4);
    __threadfence();                       // acquire: invalidate stale
  }
  __syncthreads();
}

__device__ void load_beta_lds(const P& p, int bm, int j0, float* Wb0, float* Wb1, int tid){
  if (bm == 0)      { load_slice(Wb0, p.Ur1, HH, j0, HH, tid); load_slice(Wb1, p.Wr1, HH, j0, HH, tid); }
  else if (bm == 1) { load_slice(Wb0, p.Uz1, HH, j0, HH, tid); load_slice(Wb1, p.Wz1, HH, j0, HH, tid); }
  else if (bm == 2) { load_slice(Wb0, p.Wh1, HH, j0, HH, tid); }
  else if (bm == 3) { load_slice(Wb0, p.Ur0, HH, j0, HH, tid); load_slice(Wb1, p.Wr0, DD, j0, DD, tid); }
  else              { load_slice(Wb0, p.Uz0, HH, j0, HH, tid); load_slice(Wb1, p.Wz0, DD, j0, DD, tid); }
}
__device__ void load_alpha_lds(const P& p, int am, int j0, float* Wa, float* Wa2, int tid){
  if (am == 0) load_slice(Wa, p.Uh1, HH, j0, HH, tid);
  else       { load_slice(Wa, p.Uh0, HH, j0, HH, tid); load_slice(Wa2, p.Wh0, DD, j0, DD, tid); }
}

// ---- persistent cooperative kernel: 500 blocks = 4 groups x 125 ----
__global__ __launch_bounds__(NTHR, 2) void gru_coop(P p){
  __shared__ float lds[19840];   // Wb0 | Wb1 | Wa | Wa2 = 79,360 B
  float* Wb0 = lds;
  float* Wb1 = lds + 6400;
  float* Wa  = lds + 12800;
  float* Wa2 = lds + 19200;

  const int u     = blockIdx.x;
  const int g     = u / GB;
  const int r     = u % GB;
  const int gbase = g * GCOLS;
  const int tid   = threadIdx.x;
  const int ch    = tid >> 7;               // which 8 of the block's 16 cols
  const int b     = gbase + (tid & 127);    // owned batch column
  unsigned* B     = p.bar + g * 1024;

  const int bm = r / 25, bc0 = (r % 25) * 16 + ch*8;
  const int am = r / 25, ac0 = bc0;         // alpha valid for r<50

  load_beta_lds(p, bm, (r % 25) * 16, Wb0, Wb1, tid);
  if (r < 50) load_alpha_lds(p, am, (r % 25) * 16, Wa, Wa2, tid);

  // init: transpose x(0)->xta, x(1)->xtb (group col-slice)
  if (r < 40)      xpose_g(p.x,                 p.xta, r,      gbase, tid);
  else if (r < 80) xpose_g(p.x + (size_t)BB*DD, p.xtb, r - 40, gbase, tid);

  int bn = 0;
  gbar(bn++, B, r);
  if (r >= 50 && r < 75) pro_wave(p, r - 50, ch, b);
  gbar(bn++, B, r);

  const float* Wb0s = Wb0 + ch*8;
  const float* Wb1s = Wb1 + ch*8;
  const float* Was  = Wa  + ch*8;
  const float* Wa2s = Wa2 + ch*8;

  for (int t = 0; t < TT; ++t) {
    beta_wave(p, t, bm, bc0, b, Wb0s, Wb1s);
    gbar(bn++, B, r);
    if (r < 50) alpha_wave(p, t, am, ac0, b, Was, Wa2s);
    else if (r < 90)
      xpose_g(p.x + (size_t)((t+2) % TT)*BB*DD, (t & 1) ? p.xtb : p.xta,
              r - 50, gbase, tid);
    gbar(bn++, B, r);
  }
  if (r < 32) fc_wave(p, gbase + r*4 + (tid >> 6), tid & 63);
}

// ---- fallback regular-launch path (same role mapping) ----
__global__ __launch_bounds__(NTHR) void k_init(P p){
  const int u = blockIdx.x, g = u / GB, r = u % GB, tid = threadIdx.x;
  const int gbase = g * GCOLS;
  if (r < 40)      xpose_g(p.x,                 p.xta, r,      gbase, tid);
  else if (r < 80) xpose_g(p.x + (size_t)BB*DD, p.xtb, r - 40, gbase, tid);
}
__global__ __launch_bounds__(NTHR) void k_pro(P p){
  const int u = blockIdx.x, g = u / GB, r = u % GB, tid = threadIdx.x;
  if (r >= 50 && r < 75)
    pro_wave(p, r - 50, tid >> 7, g*GCOLS + (tid & 127));
}
__global__ __launch_bounds__(NTHR) void k_beta(P p, int t){
  __shared__ float lds[12800];
  const int u = blockIdx.x, g = u / GB, r = u % GB, tid = threadIdx.x;
  const int bm = r / 25, ct = (r % 25) * 16, ch = tid >> 7;
  load_beta_lds(p, bm, ct, lds, lds + 6400, tid);
  __syncthreads();
  beta_wave(p, t, bm, ct + ch*8, g*GCOLS + (tid & 127), lds + ch*8, lds + 6400 + ch*8);
}
__global__ __launch_bounds__(NTHR) void k_alpha(P p, int t){
  __shared__ float lds[7040];
  const int u = blockIdx.x, g = u / GB, r = u % GB, tid = threadIdx.x;
  const int gbase = g * GCOLS;
  if (r < 50) {
    const int am = r / 25, ct = (r % 25) * 16, ch = tid >> 7;
    load_alpha_lds(p, am, ct, lds, lds + 6400, tid);
    __syncthreads();
    alpha_wave(p, t, am, ct + ch*8, gbase + (tid & 127), lds + ch*8, lds + 6400 + ch*8);
  } else if (r < 90) {
    xpose_g(p.x + (size_t)((t+2) % TT)*BB*DD, (t & 1) ? p.xtb : p.xta,
            r - 50, gbase, tid);
  }
}
__global__ __launch_bounds__(NTHR) void k_fc(P p){
  const int u = blockIdx.x, g = u / GB, r = u % GB;
  if (r < 32) fc_wave(p, g*GCOLS + r*4 + (threadIdx.x >> 6), threadIdx.x & 63);
}

extern "C" void kernel_launch(void* const* d_in, const int* in_sizes, int n_in,
                              void* d_out, int out_size, void* d_ws, size_t ws_size,
                              hipStream_t stream) {
  P p;
  p.x   = (const float*)d_in[0];
  p.Wh0 = (const float*)d_in[1];  p.bh0 = (const float*)d_in[2];
  p.Wz0 = (const float*)d_in[3];  p.bz0 = (const float*)d_in[4];
  p.Wr0 = (const float*)d_in[5];  p.br0 = (const float*)d_in[6];
  p.Uh0 = (const float*)d_in[7];  p.Uz0 = (const float*)d_in[8];  p.Ur0 = (const float*)d_in[9];
  p.Wh1 = (const float*)d_in[10]; p.bh1 = (const float*)d_in[11];
  p.Wz1 = (const float*)d_in[12]; p.bz1 = (const float*)d_in[13];
  p.Wr1 = (const float*)d_in[14]; p.br1 = (const float*)d_in[15];
  p.Uh1 = (const float*)d_in[16]; p.Uz1 = (const float*)d_in[17]; p.Ur1 = (const float*)d_in[18];
  p.Wfc = (const float*)d_in[19]; p.bfc = (const float*)d_in[20];

  float* ws = (float*)d_ws;
  const size_t SZ = (size_t)BB * HH;
  p.h0a  = ws + 0*SZ;  p.h0b  = ws + 1*SZ;
  p.h1a  = ws + 2*SZ;  p.h1b  = ws + 3*SZ;
  p.rt1  = ws + 4*SZ;  p.zt1  = ws + 5*SZ;  p.ah1p = ws + 6*SZ;
  p.rt0n = ws + 7*SZ;  p.zt0n = ws + 8*SZ;
  p.xta  = ws + 9*SZ;
  p.xtb  = p.xta + (size_t)BB*DD;
  p.bar  = (unsigned*)(p.xtb + (size_t)BB*DD);
  p.out  = (float*)d_out;

  hipMemsetAsync(p.h1a, 0, SZ*sizeof(float), stream);     // h1(-1) = 0
  hipMemsetAsync(p.bar, 0, GRP*1024*sizeof(unsigned), stream);

  void* args[] = { &p };
  hipError_t err = hipLaunchCooperativeKernel((const void*)gru_coop, dim3(NBLK),
                                              dim3(NTHR), args, 0, stream);
  if (err != hipSuccess) {
    k_init<<<dim3(NBLK), dim3(NTHR), 0, stream>>>(p);
    k_pro<<<dim3(NBLK), dim3(NTHR), 0, stream>>>(p);
    for (int t = 0; t < TT; ++t) {
      k_beta <<<dim3(NBLK), dim3(NTHR), 0, stream>>>(p, t);
      k_alpha<<<dim3(NBLK), dim3(NTHR), 0, stream>>>(p, t);
    }
    k_fc<<<dim3(NBLK), dim3(NTHR), 0, stream>>>(p);
  }
}